// Round 11
// baseline (121.870 us; speedup 1.0000x reference)
//
#include <hip/hip_runtime.h>
#include <hip/hip_bf16.h>

#define BBATCH 16
#define NPTS   4096
#define ROWS_PER_BLOCK 256              /* 4 waves x 2 afrags x 32 rows */
#define NCHUNKS 16                      /* row-chunks per (dir,batch) */
#define MCHUNK 512                      /* db points per LDS chunk */
#define NMCHUNKS 8                      /* NPTS/MCHUNK */
#define TILES 16                        /* MCHUNK/32 */

typedef unsigned short ushort_t;
typedef __attribute__((ext_vector_type(8)))  short bf16x8;
typedef __attribute__((ext_vector_type(16))) float f32x16;

__device__ __forceinline__ ushort_t bfh(float v) {
  union { __hip_bfloat16 h; ushort_t u; } c; c.h = __float2bfloat16(v); return c.u;
}
__device__ __forceinline__ float bff(ushort_t u) {
  union { ushort_t u; __hip_bfloat16 h; } c; c.u = u; return __bfloat162float(c.h);
}

// K=16 bf16 record formats (hi/lo split -> f32-accurate distances):
//   A(p,s) = [ph0,ph1,ph2, pl0,pl1,pl2, ph0,ph1,ph2, sh,sl, 1,1, 0,0,0]
//   B(z,q) = [zh0,zh1,zh2, zh0,zh1,zh2, zl0,zl1,zl2, 1,1, qh,ql, 0,0,0], z=-2y
//   dot(A,B) = s + q - 2 p.y  (missing ll cross-term ~1e-6: negligible)

// ---------------------------------------------------------------------------
// DISCRIMINATOR ROUND: kernel body identical to round 10. Launched TWICE:
// real -> d_out, echo -> d_ws (poisoned scratch, never read). Delta-total
// vs round 10 = warm kernel time; if >=40us the echo shows in top-5 with
// its own counters. Resolves "kernel ~12us + 75us harness floor" vs
// "kernel ~40us stalled" before further optimization.
// ---------------------------------------------------------------------------
__global__ __launch_bounds__(256) void chamfer_fused(
    const float* __restrict__ Xv, const float* __restrict__ Yv,
    const float* __restrict__ Tm, float* __restrict__ out)
{
  __shared__ uint4 Blds[2][MCHUNK];   // [lo/hi][pt]  16 KB
  __shared__ float blocksum;

  const int tid = threadIdx.x, lane = tid & 63, wid = tid >> 6;
  const int l31 = lane & 31, kh = lane >> 5;
  const int dir = blockIdx.x >> 8;        // 512 blocks: dir | b(4b) | nch(4b)
  const int rem = blockIdx.x & 255;
  const int b   = rem >> 4;
  const int nch = rem & 15;

  if (tid == 0) blocksum = 0.f;

  // T is block-uniform -> SGPRs. Column 3 == [0,0,0,1]^T -> w==1 exactly.
  const float* T = Tm + b * 16;

  const float* Qs = dir ? Yv : Xv;   // query-side raw points
  const float* Ds = dir ? Xv : Yv;   // db-side raw points
  const bool tq = (dir == 1);        // transform query side (else db side)
  const ushort_t ONE = 0x3F80;

  // ---- two A fragments: rows qbase+0..31 (a0) and +32..63 (a1) ----
  bf16x8 afrag0, afrag1;
#pragma unroll
  for (int a = 0; a < 2; ++a) {
    int qidx = b*NPTS + nch*ROWS_PER_BLOCK + wid*64 + a*32 + l31;
    float p0 = Qs[qidx*3], p1 = Qs[qidx*3+1], p2 = Qs[qidx*3+2];
    if (tq) {
      float t0 = p0*T[0] + p1*T[4] + p2*T[8]  + T[12];
      float t1 = p0*T[1] + p1*T[5] + p2*T[9]  + T[13];
      float t2 = p0*T[2] + p1*T[6] + p2*T[10] + T[14];
      p0 = t0; p1 = t1; p2 = t2;
    }
    float sq = p0*p0 + p1*p1 + p2*p2;
    ushort_t h0=bfh(p0), h1=bfh(p1), h2=bfh(p2);
    ushort_t l0=bfh(p0-bff(h0)), l1=bfh(p1-bff(h1)), l2=bfh(p2-bff(h2));
    ushort_t sh=bfh(sq), sl=bfh(sq-bff(sh));
    union { ushort_t r[8]; bf16x8 v; } alo, ahi;
    alo.r[0]=h0; alo.r[1]=h1; alo.r[2]=h2; alo.r[3]=l0;
    alo.r[4]=l1; alo.r[5]=l2; alo.r[6]=h0; alo.r[7]=h1;
    ahi.r[0]=h2; ahi.r[1]=sh; ahi.r[2]=sl; ahi.r[3]=ONE;
    ahi.r[4]=ONE; ahi.r[5]=0; ahi.r[6]=0; ahi.r[7]=0;
    bf16x8 f = kh ? ahi.v : alo.v;
    if (a == 0) afrag0 = f; else afrag1 = f;
  }

  float rm0[16], rm1[16];
#pragma unroll
  for (int i = 0; i < 16; i++) { rm0[i] = 3e38f; rm1[i] = 3e38f; }

  const float* dbase = Ds + (size_t)b * NPTS * 3;

  for (int ch = 0; ch < NMCHUNKS; ++ch) {
    __syncthreads();   // WAR: previous chunk's reads done before overwrite

    // pack 2 db points per thread: transform (dir==0) + hi/lo split -> LDS
#pragma unroll
    for (int half = 0; half < 2; ++half) {
      int s = tid + half * 256;
      const float* pp = dbase + (size_t)(ch * MCHUNK + s) * 3;
      float r0 = pp[0], r1 = pp[1], r2 = pp[2];
      if (!tq) {
        float t0 = r0*T[0] + r1*T[4] + r2*T[8]  + T[12];
        float t1 = r0*T[1] + r1*T[5] + r2*T[9]  + T[13];
        float t2 = r0*T[2] + r1*T[6] + r2*T[10] + T[14];
        r0 = t0; r1 = t1; r2 = t2;
      }
      float sq = r0*r0 + r1*r1 + r2*r2;
      float z0 = -2.f*r0, z1 = -2.f*r1, z2 = -2.f*r2;
      ushort_t h0=bfh(z0), h1=bfh(z1), h2=bfh(z2);
      ushort_t l0=bfh(z0-bff(h0)), l1=bfh(z1-bff(h1)), l2=bfh(z2-bff(h2));
      ushort_t sh=bfh(sq), sl=bfh(sq-bff(sh));
      union { ushort_t r[8]; uint4 q; } lo, hi;
      lo.r[0]=h0; lo.r[1]=h1; lo.r[2]=h2; lo.r[3]=h0;
      lo.r[4]=h1; lo.r[5]=h2; lo.r[6]=l0; lo.r[7]=l1;
      hi.r[0]=l2; hi.r[1]=ONE; hi.r[2]=ONE; hi.r[3]=sh;
      hi.r[4]=sl; hi.r[5]=0; hi.r[6]=0; hi.r[7]=0;
      Blds[0][s] = lo.q;
      Blds[1][s] = hi.q;
    }
    __syncthreads();

    const bf16x8* bbase = (const bf16x8*)Blds[kh];
#pragma unroll
    for (int tt = 0; tt < TILES; ++tt) {
      bf16x8 bfrag = bbase[tt * 32 + l31];
      f32x16 zc = {};
      f32x16 D0 = __builtin_amdgcn_mfma_f32_32x32x16_bf16(afrag0, bfrag, zc, 0, 0, 0);
      f32x16 D1 = __builtin_amdgcn_mfma_f32_32x32x16_bf16(afrag1, bfrag, zc, 0, 0, 0);
#pragma unroll
      for (int i = 0; i < 16; i++) {
        rm0[i] = fminf(rm0[i], D0[i]);
        rm1[i] = fminf(rm1[i], D1[i]);
      }
    }
  }

  // butterfly min over lane bits 0..4 (cols); each 32-lane half holds its rows
#pragma unroll
  for (int s = 1; s <= 16; s <<= 1) {
#pragma unroll
    for (int i = 0; i < 16; i++) {
      rm0[i] = fminf(rm0[i], __shfl_xor(rm0[i], s, 64));
      rm1[i] = fminf(rm1[i], __shfl_xor(rm1[i], s, 64));
    }
  }
  float rs = 0.f;
#pragma unroll
  for (int i = 0; i < 16; i++) rs += fmaxf(rm0[i], 0.f) + fmaxf(rm1[i], 0.f);
  if (l31 == 0) atomicAdd(&blocksum, rs);   // lanes 0,32 = the two row-halves
  __syncthreads();
  if (tid == 0) atomicAdd(out, blocksum);
}

extern "C" void kernel_launch(void* const* d_in, const int* in_sizes, int n_in,
                              void* d_out, int out_size, void* d_ws, size_t ws_size,
                              hipStream_t stream) {
  const float* Xv = (const float*)d_in[0];   // [B,N,3]
  const float* Yv = (const float*)d_in[1];   // [B,M,3]
  const float* Tm = (const float*)d_in[2];   // [B,4,4]
  float* out = (float*)d_out;
  float* echo = (float*)d_ws;   // poisoned scratch; echo accumulates garbage, never read

  hipMemsetAsync(out, 0, sizeof(float), stream);
  chamfer_fused<<<2 * BBATCH * NCHUNKS, 256, 0, stream>>>(Xv, Yv, Tm, out);
  chamfer_fused<<<2 * BBATCH * NCHUNKS, 256, 0, stream>>>(Xv, Yv, Tm, echo);
}

// Round 13
// 99.333 us; speedup vs baseline: 1.2269x; 1.2269x over previous
//
#include <hip/hip_runtime.h>
#include <hip/hip_bf16.h>

#define BBATCH 16
#define NPTS   4096
#define ROWS_PER_BLOCK 256    /* 4 waves x 2 afrags x 32 rows */
#define NCH    16             /* row-chunks per (dir,batch) */
#define MSPLIT 4              /* db split across blocks */
#define MPB    1024           /* db points per block = NPTS/MSPLIT */
#define MCHUNK 512            /* db points per LDS chunk */
#define NMCH   2              /* MPB/MCHUNK */
#define TILES  16             /* MCHUNK/32 */

typedef unsigned int  uint_t;
typedef unsigned short ushort_t;
typedef __attribute__((ext_vector_type(8)))  short bf16x8;
typedef __attribute__((ext_vector_type(16))) float f32x16;

__device__ __forceinline__ ushort_t bfh(float v) {
  union { __hip_bfloat16 h; ushort_t u; } c; c.h = __float2bfloat16(v); return c.u;
}
__device__ __forceinline__ float bff(ushort_t u) {
  union { ushort_t u; __hip_bfloat16 h; } c; c.u = u; return __bfloat162float(c.h);
}
__device__ __forceinline__ float min3f(float a, float b, float c) {
  return fminf(fminf(a, b), c);   // fuses to v_min3_f32
}

// K=16 bf16 record formats (hi/lo split -> f32-accurate distances):
//   A(p,s) = [ph0,ph1,ph2, pl0,pl1,pl2, ph0,ph1,ph2, sh,sl, 1,1, 0,0,0]
//   B(z,q) = [zh0,zh1,zh2, zh0,zh1,zh2, zl0,zl1,zl2, 1,1, qh,ql, 0,0,0], z=-2y
//   dot(A,B) = s + q - 2 p.y  (full squared distance)

// ---------------------------------------------------------------------------
// Round-11 diagnosis: kernel ~49us, MfmaUtil 12.6%, VALUBusy 46%, occupancy
// 17.7% -- latency-bound at 2 blocks/CU. Fixes here:
//  * MSPLIT=4 -> grid 2048 blocks (~4/CU resident, ~16 waves/CU)
//  * b-pair reuse: 2 ds_read feed 4 MFMA; min3 -> 1 VALU per 128 distances
//  * sequential D-pairs cap live regs (~100 VGPR, no cap, no spill)
//  * cross-block row-min combine: global atomicMin (u32, clamped >=0)
// ---------------------------------------------------------------------------
__global__ __launch_bounds__(256) void chamfer_fused(
    const float* __restrict__ Xv, const float* __restrict__ Yv,
    const float* __restrict__ Tm, uint_t* __restrict__ rminG)
{
  __shared__ uint4 Blds[2][MCHUNK];   // [lo/hi][pt]  16 KB
  const int tid = threadIdx.x, lane = tid & 63, wid = tid >> 6;
  const int l31 = lane & 31, kh = lane >> 5;
  const int dir = blockIdx.x >> 10;            // 2048 = dir|b(4)|nch(4)|ms(2)
  const int rem = blockIdx.x & 1023;
  const int b   = rem >> 6;
  const int nch = (rem >> 2) & 15;
  const int ms  = rem & 3;

  const float* T = Tm + b * 16;       // block-uniform -> SGPRs; col3=[0,0,0,1]
  const float* Qs = dir ? Yv : Xv;
  const float* Ds = dir ? Xv : Yv;
  const bool tq = (dir == 1);
  const ushort_t ONE = 0x3F80;

  // ---- two A fragments: rows +0..31 (a0), +32..63 (a1) ----
  bf16x8 afrag0, afrag1;
#pragma unroll
  for (int a = 0; a < 2; ++a) {
    int qidx = b*NPTS + nch*ROWS_PER_BLOCK + wid*64 + a*32 + l31;
    float p0 = Qs[qidx*3], p1 = Qs[qidx*3+1], p2 = Qs[qidx*3+2];
    if (tq) {
      float t0 = p0*T[0] + p1*T[4] + p2*T[8]  + T[12];
      float t1 = p0*T[1] + p1*T[5] + p2*T[9]  + T[13];
      float t2 = p0*T[2] + p1*T[6] + p2*T[10] + T[14];
      p0 = t0; p1 = t1; p2 = t2;
    }
    float sq = p0*p0 + p1*p1 + p2*p2;
    ushort_t h0=bfh(p0), h1=bfh(p1), h2=bfh(p2);
    ushort_t l0=bfh(p0-bff(h0)), l1=bfh(p1-bff(h1)), l2=bfh(p2-bff(h2));
    ushort_t sh=bfh(sq), sl=bfh(sq-bff(sh));
    union { ushort_t r[8]; bf16x8 v; } alo, ahi;
    alo.r[0]=h0; alo.r[1]=h1; alo.r[2]=h2; alo.r[3]=l0;
    alo.r[4]=l1; alo.r[5]=l2; alo.r[6]=h0; alo.r[7]=h1;
    ahi.r[0]=h2; ahi.r[1]=sh; ahi.r[2]=sl; ahi.r[3]=ONE;
    ahi.r[4]=ONE; ahi.r[5]=0; ahi.r[6]=0; ahi.r[7]=0;
    bf16x8 f = kh ? ahi.v : alo.v;
    if (a == 0) afrag0 = f; else afrag1 = f;
  }

  float rm0[16], rm1[16];
#pragma unroll
  for (int i = 0; i < 16; i++) { rm0[i] = 3e38f; rm1[i] = 3e38f; }

  const float* dbase = Ds + ((size_t)b * NPTS + ms * MPB) * 3;

  for (int ch = 0; ch < NMCH; ++ch) {
    __syncthreads();
#pragma unroll
    for (int half = 0; half < 2; ++half) {
      int s = tid + half * 256;
      const float* pp = dbase + (size_t)(ch * MCHUNK + s) * 3;
      float r0 = pp[0], r1 = pp[1], r2 = pp[2];
      if (!tq) {
        float t0 = r0*T[0] + r1*T[4] + r2*T[8]  + T[12];
        float t1 = r0*T[1] + r1*T[5] + r2*T[9]  + T[13];
        float t2 = r0*T[2] + r1*T[6] + r2*T[10] + T[14];
        r0 = t0; r1 = t1; r2 = t2;
      }
      float sq = r0*r0 + r1*r1 + r2*r2;
      float z0 = -2.f*r0, z1 = -2.f*r1, z2 = -2.f*r2;
      ushort_t h0=bfh(z0), h1=bfh(z1), h2=bfh(z2);
      ushort_t l0=bfh(z0-bff(h0)), l1=bfh(z1-bff(h1)), l2=bfh(z2-bff(h2));
      ushort_t sh=bfh(sq), sl=bfh(sq-bff(sh));
      union { ushort_t r[8]; uint4 q; } lo, hi;
      lo.r[0]=h0; lo.r[1]=h1; lo.r[2]=h2; lo.r[3]=h0;
      lo.r[4]=h1; lo.r[5]=h2; lo.r[6]=l0; lo.r[7]=l1;
      hi.r[0]=l2; hi.r[1]=ONE; hi.r[2]=ONE; hi.r[3]=sh;
      hi.r[4]=sl; hi.r[5]=0; hi.r[6]=0; hi.r[7]=0;
      Blds[0][s] = lo.q;
      Blds[1][s] = hi.q;
    }
    __syncthreads();

    const bf16x8* bbase = (const bf16x8*)Blds[kh];
#pragma unroll
    for (int tp = 0; tp < TILES/2; ++tp) {
      bf16x8 b0 = bbase[tp*64 + l31];
      bf16x8 b1 = bbase[tp*64 + 32 + l31];
      f32x16 zc = {};
      // sequential D-pairs: <=2 D tiles live at once
      f32x16 D0 = __builtin_amdgcn_mfma_f32_32x32x16_bf16(afrag0, b0, zc, 0, 0, 0);
      f32x16 D1 = __builtin_amdgcn_mfma_f32_32x32x16_bf16(afrag0, b1, zc, 0, 0, 0);
#pragma unroll
      for (int i = 0; i < 16; i++) rm0[i] = min3f(rm0[i], D0[i], D1[i]);
      f32x16 D2 = __builtin_amdgcn_mfma_f32_32x32x16_bf16(afrag1, b0, zc, 0, 0, 0);
      f32x16 D3 = __builtin_amdgcn_mfma_f32_32x32x16_bf16(afrag1, b1, zc, 0, 0, 0);
#pragma unroll
      for (int i = 0; i < 16; i++) rm1[i] = min3f(rm1[i], D2[i], D3[i]);
    }
  }

  // butterfly min over lane bits 0..4 (cols within this block's db range)
#pragma unroll
  for (int s = 1; s <= 16; s <<= 1) {
#pragma unroll
    for (int i = 0; i < 16; i++) {
      rm0[i] = fminf(rm0[i], __shfl_xor(rm0[i], s, 64));
      rm1[i] = fminf(rm1[i], __shfl_xor(rm1[i], s, 64));
    }
  }

  // cross-block combine: clamp then atomicMin (uint order valid for >=0)
  if (l31 == 0) {
    uint_t* rbase = rminG + ((size_t)(dir * BBATCH + b) << 12)
                  + nch * ROWS_PER_BLOCK + wid * 64;
#pragma unroll
    for (int i = 0; i < 16; i++) {
      int row = (i & 3) + 8 * (i >> 2) + 4 * kh;   // D-layout row (m74/m101)
      atomicMin(rbase + row,      __float_as_uint(fmaxf(rm0[i], 0.f)));
      atomicMin(rbase + 32 + row, __float_as_uint(fmaxf(rm1[i], 0.f)));
    }
  }
}

// ---------------------------------------------------------------------------
// reduce: sum all 2*B*N row-mins (already clamped) into out[0].
// ---------------------------------------------------------------------------
__global__ __launch_bounds__(256) void reduce_rows(
    const uint_t* __restrict__ rminG, float* __restrict__ out)
{
  __shared__ float wsum[4];
  float s = 0.f;
  for (int i = blockIdx.x * 256 + threadIdx.x; i < 2 * BBATCH * NPTS; i += gridDim.x * 256)
    s += __uint_as_float(rminG[i]);
#pragma unroll
  for (int o = 32; o > 0; o >>= 1) s += __shfl_down(s, o, 64);
  int w = threadIdx.x >> 6, lane = threadIdx.x & 63;
  if (lane == 0) wsum[w] = s;
  __syncthreads();
  if (threadIdx.x == 0) atomicAdd(out, wsum[0] + wsum[1] + wsum[2] + wsum[3]);
}

extern "C" void kernel_launch(void* const* d_in, const int* in_sizes, int n_in,
                              void* d_out, int out_size, void* d_ws, size_t ws_size,
                              hipStream_t stream) {
  const float* Xv = (const float*)d_in[0];   // [B,N,3]
  const float* Yv = (const float*)d_in[1];   // [B,M,3]
  const float* Tm = (const float*)d_in[2];   // [B,4,4]
  float* out = (float*)d_out;
  uint_t* rminG = (uint_t*)d_ws;             // 2*16*4096 u32 = 512 KB

  hipMemsetAsync(rminG, 0x7F, (size_t)2 * BBATCH * NPTS * 4, stream);
  hipMemsetAsync(out, 0, sizeof(float), stream);
  chamfer_fused<<<2 * BBATCH * NCH * MSPLIT, 256, 0, stream>>>(Xv, Yv, Tm, rminG);
  reduce_rows<<<128, 256, 0, stream>>>(rminG, out);
}